// Round 10
// baseline (209.877 us; speedup 1.0000x reference)
//
#include <hip/hip_runtime.h>

#define D 1024      // in_features
#define E 64        // num experts
#define TPB 256     // threads per block (4 waves)
#define TOKS 64     // tokens per block-tile (16 per wave)
#define NCH 8       // chunks of 128 k (4 MFMA k-steps) -> 8 barrier phases
#define CHB 32768   // bytes per staged W chunk (4 ks x 8 records x 1KB)
#define NBLK 256    // DIAGNOSTIC: 1 block/CU, 2 sequential tiles -> kernel
#define NTILE 2     //  becomes visible in rocprof top-5 (fills are ~78us)

typedef __attribute__((ext_vector_type(8))) short bf16x8;
typedef __attribute__((ext_vector_type(8))) unsigned short u16x8;
typedef __attribute__((ext_vector_type(4))) float f32x4;
typedef __attribute__((ext_vector_type(4))) unsigned int u32x4;

__device__ __forceinline__ unsigned short bf16_rne(float f) {
    unsigned u = __builtin_bit_cast(unsigned, f);
    u += 0x7fffu + ((u >> 16) & 1u);
    return (unsigned short)(u >> 16);
}
__device__ __forceinline__ float bf16_to_f(unsigned short h) {
    unsigned u = ((unsigned)h) << 16;
    return __builtin_bit_cast(float, u);
}
__device__ __forceinline__ unsigned cvt_pk_bf16(float a, float b) {
    // dst[15:0]=bf16_rne(a), dst[31:16]=bf16_rne(b) — bit-identical to bf16_rne
    unsigned r;
    asm("v_cvt_pk_bf16_f32 %0, %1, %2" : "=v"(r) : "v"(a), "v"(b));
    return r;
}
__device__ __forceinline__ float lo_val(unsigned p) {
    return __builtin_bit_cast(float, p << 16);
}
__device__ __forceinline__ float hi_val(unsigned p) {
    return __builtin_bit_cast(float, p & 0xffff0000u);
}

// Split 8 fp32 into bf16 hi (RNE) + bf16 lo (RNE of exact residual).
// Bitwise-identical values to the original verified split_hi_lo scheme.
__device__ __forceinline__ void split8_rne(f32x4 a, f32x4 b, bf16x8& hv, bf16x8& lv) {
    unsigned h0 = cvt_pk_bf16(a[0], a[1]);
    unsigned h1 = cvt_pk_bf16(a[2], a[3]);
    unsigned h2 = cvt_pk_bf16(b[0], b[1]);
    unsigned h3 = cvt_pk_bf16(b[2], b[3]);
    unsigned l0 = cvt_pk_bf16(a[0] - lo_val(h0), a[1] - hi_val(h0));
    unsigned l1 = cvt_pk_bf16(a[2] - lo_val(h1), a[3] - hi_val(h1));
    unsigned l2 = cvt_pk_bf16(b[0] - lo_val(h2), b[1] - hi_val(h2));
    unsigned l3 = cvt_pk_bf16(b[2] - lo_val(h3), b[3] - hi_val(h3));
    hv = __builtin_bit_cast(bf16x8, (u32x4){h0, h1, h2, h3});
    lv = __builtin_bit_cast(bf16x8, (u32x4){l0, l1, l2, l3});
}

// ---------------------------------------------------------------------------
// One-time prep (proven): W -> RNE hi/lo bf16 in MFMA B-fragment lane order.
// Record f = (ks*8 + nt*2 + hl): 64 lanes x 16B; lane (n,q) holds
// W[nt*16+n][ks*32 + q*8 + 0..7].  256 KB -> d_ws.
// ---------------------------------------------------------------------------
__global__ __launch_bounds__(256) void router_prep(
        const float* __restrict__ W, unsigned short* __restrict__ Ws) {
    int t = blockIdx.x * 256 + threadIdx.x;  // 0..8191
    int lane = t & 63;
    int nt = (t >> 6) & 3;
    int ks = t >> 8;
    int n = lane & 15, q = lane >> 4;
    const float* src = W + (size_t)(nt * 16 + n) * D + ks * 32 + q * 8;
    u16x8 hv, lv;
#pragma unroll
    for (int j = 0; j < 8; ++j) {
        float v = src[j];
        unsigned short h = bf16_rne(v);
        hv[j] = h;
        lv[j] = bf16_rne(v - bf16_to_f(h));
    }
    size_t base = ((size_t)(ks * 8 + nt * 2) * 64 + lane) * 8;
    *(u16x8*)(Ws + base)          = hv;      // hl = 0
    *(u16x8*)(Ws + base + 64 * 8) = lv;      // hl = 1
}

// ---------------------------------------------------------------------------
// Main: EXACT r8 structure (the measured best), run as 256 blocks x 2
// sequential tiles instead of 512 blocks, so the dispatch exceeds the ~78us
// harness fills and appears in rocprof top-5 with counters.  This measures
// the fully-exposed per-phase cost (no cross-block overlap).
// ---------------------------------------------------------------------------
__global__ __launch_bounds__(TPB) void router_main(
        const float* __restrict__ x, const unsigned short* __restrict__ Ws,
        const float* __restrict__ bias, float* __restrict__ out, int T) {
    __shared__ __align__(16) union SM {
        unsigned char buf[2][CHB];          // 64 KB: double-buffered W chunks
        float ls[TOKS][E + 1];              // epilogue logits (union reuse)
    } sm;
    __shared__ float sbias[E];

    const int tid  = threadIdx.x;
    const int lane = tid & 63;
    const int wid  = tid >> 6;
    const int n    = lane & 15;
    const int q    = lane >> 4;

    if (tid < E) sbias[tid] = bias[tid];

    const u32x4* gws = (const u32x4*)Ws;

#define ISSUEW(c_) do {                                               \
        const u32x4* _g = gws + (size_t)(c_) * 2048 + tid;            \
        W0 = _g[0];    W1 = _g[256];  W2 = _g[512];  W3 = _g[768];    \
        W4 = _g[1024]; W5 = _g[1280]; W6 = _g[1536]; W7 = _g[1792];   \
    } while (0)

#define WRITEW(bi_) do {                                              \
        u32x4* _l = (u32x4*)sm.buf[bi_] + tid;                        \
        _l[0]    = W0; _l[256]  = W1; _l[512]  = W2; _l[768]  = W3;   \
        _l[1024] = W4; _l[1280] = W5; _l[1536] = W6; _l[1792] = W7;   \
    } while (0)

#define ISSUEA(p0u,p0v,p1u,p1v,p2u,p2v,p3u,p3v, c_) do {              \
        const float* _b = arow + (size_t)(c_) * 128;                  \
        p0u = *(const f32x4*)(_b);       p0v = *(const f32x4*)(_b + 4);   \
        p1u = *(const f32x4*)(_b + 32);  p1v = *(const f32x4*)(_b + 36);  \
        p2u = *(const f32x4*)(_b + 64);  p2v = *(const f32x4*)(_b + 68);  \
        p3u = *(const f32x4*)(_b + 96);  p3v = *(const f32x4*)(_b + 100); \
    } while (0)

#define MFMA __builtin_amdgcn_mfma_f32_16x16x32_bf16
// One MFMA k-step: A pair (au,av) against the 8 frag-records of k-step ksl.
// Accumulation order identical to all passing rounds.
#define COMPSTEP(bi_, ksl_, au_, av_) do {                            \
        bf16x8 ah, al;                                                \
        split8_rne(au_, av_, ah, al);                                 \
        const char* _p = (const char*)sm.buf[bi_] + (ksl_) * 8192 + lane * 16; \
        {                                                             \
            bf16x8 bh = *(const bf16x8*)(_p);                         \
            bf16x8 bl = *(const bf16x8*)(_p + 1024);                  \
            c0 = MFMA(ah, bh, c0, 0, 0, 0);                           \
            c0 = MFMA(al, bh, c0, 0, 0, 0);                           \
            c0 = MFMA(ah, bl, c0, 0, 0, 0);                           \
        }                                                             \
        {                                                             \
            bf16x8 bh = *(const bf16x8*)(_p + 2048);                  \
            bf16x8 bl = *(const bf16x8*)(_p + 3072);                  \
            c1 = MFMA(ah, bh, c1, 0, 0, 0);                           \
            c1 = MFMA(al, bh, c1, 0, 0, 0);                           \
            c1 = MFMA(ah, bl, c1, 0, 0, 0);                           \
        }                                                             \
        {                                                             \
            bf16x8 bh = *(const bf16x8*)(_p + 4096);                  \
            bf16x8 bl = *(const bf16x8*)(_p + 5120);                  \
            c2 = MFMA(ah, bh, c2, 0, 0, 0);                           \
            c2 = MFMA(al, bh, c2, 0, 0, 0);                           \
            c2 = MFMA(ah, bl, c2, 0, 0, 0);                           \
        }                                                             \
        {                                                             \
            bf16x8 bh = *(const bf16x8*)(_p + 6144);                  \
            bf16x8 bl = *(const bf16x8*)(_p + 7168);                  \
            c3 = MFMA(ah, bh, c3, 0, 0, 0);                           \
            c3 = MFMA(al, bh, c3, 0, 0, 0);                           \
            c3 = MFMA(ah, bl, c3, 0, 0, 0);                           \
        }                                                             \
    } while (0)

#define COMPCHUNK(bi_, p0u,p0v,p1u,p1v,p2u,p2v,p3u,p3v) do {          \
        COMPSTEP(bi_, 0, p0u, p0v);                                   \
        COMPSTEP(bi_, 1, p1u, p1v);                                   \
        COMPSTEP(bi_, 2, p2u, p2v);                                   \
        COMPSTEP(bi_, 3, p3u, p3v);                                   \
    } while (0)

    for (int tile = 0; tile < NTILE; ++tile) {
        const int t0 = (blockIdx.x + tile * NBLK) * TOKS;
        const float* arow = x + (size_t)(t0 + wid * 16 + n) * D + q * 8;

        f32x4 c0 = {0.f, 0.f, 0.f, 0.f}, c1 = c0, c2 = c0, c3 = c0;
        u32x4 W0, W1, W2, W3, W4, W5, W6, W7;             // named batches only
        f32x4 A0u, A0v, A1u, A1v, A2u, A2v, A3u, A3v;     // (rule #20)
        f32x4 N0u, N0v, N1u, N1v, N2u, N2v, N3u, N3v;

        // ---- prologue: chunk 0 into buf0, A chunk 0 into regs ----
        ISSUEW(0);
        ISSUEA(A0u,A0v,A1u,A1v,A2u,A2v,A3u,A3v, 0);
        WRITEW(0);
        __syncthreads();

        // ---- 8 phases, one barrier each ----
        for (int c = 0; c < NCH; c += 2) {
            ISSUEW(c + 1);
            ISSUEA(N0u,N0v,N1u,N1v,N2u,N2v,N3u,N3v, c + 1);
            COMPCHUNK(0, A0u,A0v,A1u,A1v,A2u,A2v,A3u,A3v);
            WRITEW(1);
            __syncthreads();
            ISSUEW((c + 2) & (NCH - 1));
            ISSUEA(A0u,A0v,A1u,A1v,A2u,A2v,A3u,A3v, (c + 2) & (NCH - 1));
            COMPCHUNK(1, N0u,N0v,N1u,N1v,N2u,N2v,N3u,N3v);
            WRITEW(0);
            __syncthreads();
        }

        // ---- epilogue: logits (+bias) into union'd LDS, softmax + top-2 ----
        {
            const int row = wid * 16 + q * 4;
#define STORE_C(c_, nt_) do {                                         \
                int col = (nt_) * 16 + n;                             \
                float bv = sbias[col];                                \
                sm.ls[row + 0][col] = c_[0] + bv;                     \
                sm.ls[row + 1][col] = c_[1] + bv;                     \
                sm.ls[row + 2][col] = c_[2] + bv;                     \
                sm.ls[row + 3][col] = c_[3] + bv;                     \
            } while (0)
            STORE_C(c0, 0); STORE_C(c1, 1); STORE_C(c2, 2); STORE_C(c3, 3);
#undef STORE_C
        }
        __syncthreads();

        if (tid < TOKS) {
            float m1 = -3.4e38f, m2 = -3.4e38f;
            int i1 = 0, i2 = 0;
            for (int e = 0; e < E; ++e) {
                float v = sm.ls[tid][e];
                if (v > m1) { m2 = m1; i2 = i1; m1 = v; i1 = e; }
                else if (v > m2) { m2 = v; i2 = e; }
            }
            float Z = 0.f;
            for (int e = 0; e < E; ++e) Z += __expf(sm.ls[tid][e] - m1);
            float inv = 1.f / Z;
            int gt = t0 + tid;
            out[(size_t)gt * 2]     = inv;                  // exp(m1-m1)/Z
            out[(size_t)gt * 2 + 1] = __expf(m2 - m1) * inv;
            float* oi = out + (size_t)T * 2;
            oi[(size_t)gt * 2]     = (float)i1;             // indices as floats
            oi[(size_t)gt * 2 + 1] = (float)i2;
        }
        __syncthreads();   // ls reads done before next tile's staging reuses LDS
    }
}

extern "C" void kernel_launch(void* const* d_in, const int* in_sizes, int n_in,
                              void* d_out, int out_size, void* d_ws, size_t ws_size,
                              hipStream_t stream) {
    const float* x = (const float*)d_in[0];
    const float* W = (const float*)d_in[1];
    const float* b = (const float*)d_in[2];
    float* out = (float*)d_out;
    unsigned short* Ws = (unsigned short*)d_ws;   // needs 256 KB
    int T = in_sizes[0] / D;                      // 32768 tokens
    hipLaunchKernelGGL(router_prep, dim3(32), dim3(256), 0, stream, W, Ws);
    hipLaunchKernelGGL(router_main, dim3(NBLK), dim3(TPB), 0, stream,
                       x, Ws, b, out, T);
}

// Round 11
// 203.655 us; speedup vs baseline: 1.0306x; 1.0306x over previous
//
#include <hip/hip_runtime.h>

#define D 1024      // in_features
#define E 64        // num experts
#define TPB 256     // threads per block (4 waves)
#define TOKS 64     // tokens per block (16 per wave)
#define NCH 8       // chunks of 128 k (4 MFMA k-steps) -> 8 barrier phases
#define CHB 32768   // bytes per staged W chunk (4 ks x 8 records x 1KB)

typedef __attribute__((ext_vector_type(8))) short bf16x8;
typedef __attribute__((ext_vector_type(8))) unsigned short u16x8;
typedef __attribute__((ext_vector_type(4))) float f32x4;
typedef __attribute__((ext_vector_type(4))) unsigned int u32x4;

__device__ __forceinline__ unsigned short bf16_rne(float f) {
    unsigned u = __builtin_bit_cast(unsigned, f);
    u += 0x7fffu + ((u >> 16) & 1u);
    return (unsigned short)(u >> 16);
}
__device__ __forceinline__ float bf16_to_f(unsigned short h) {
    unsigned u = ((unsigned)h) << 16;
    return __builtin_bit_cast(float, u);
}
__device__ __forceinline__ unsigned cvt_pk_bf16(float a, float b) {
    // dst[15:0]=bf16_rne(a), dst[31:16]=bf16_rne(b) — bit-identical to bf16_rne
    unsigned r;
    asm("v_cvt_pk_bf16_f32 %0, %1, %2" : "=v"(r) : "v"(a), "v"(b));
    return r;
}
__device__ __forceinline__ float lo_val(unsigned p) {
    return __builtin_bit_cast(float, p << 16);
}
__device__ __forceinline__ float hi_val(unsigned p) {
    return __builtin_bit_cast(float, p & 0xffff0000u);
}

// Direct global->LDS DMA (gfx950).  LDS dest must be wave-uniform base +
// lane*16 (m104); our W record layout is exactly that.  size=16 literal.
__device__ __forceinline__ void gload16(const void* g, void* l) {
    __builtin_amdgcn_global_load_lds(
        (const __attribute__((address_space(1))) unsigned int*)g,
        (__attribute__((address_space(3))) unsigned int*)l, 16, 0, 0);
}

// Split 8 fp32 into bf16 hi (RNE) + bf16 lo (RNE of exact residual).
// Bitwise-identical values to the original verified split_hi_lo scheme.
__device__ __forceinline__ void split8_rne(f32x4 a, f32x4 b, bf16x8& hv, bf16x8& lv) {
    unsigned h0 = cvt_pk_bf16(a[0], a[1]);
    unsigned h1 = cvt_pk_bf16(a[2], a[3]);
    unsigned h2 = cvt_pk_bf16(b[0], b[1]);
    unsigned h3 = cvt_pk_bf16(b[2], b[3]);
    unsigned l0 = cvt_pk_bf16(a[0] - lo_val(h0), a[1] - hi_val(h0));
    unsigned l1 = cvt_pk_bf16(a[2] - lo_val(h1), a[3] - hi_val(h1));
    unsigned l2 = cvt_pk_bf16(b[0] - lo_val(h2), b[1] - hi_val(h2));
    unsigned l3 = cvt_pk_bf16(b[2] - lo_val(h3), b[3] - hi_val(h3));
    hv = __builtin_bit_cast(bf16x8, (u32x4){h0, h1, h2, h3});
    lv = __builtin_bit_cast(bf16x8, (u32x4){l0, l1, l2, l3});
}

// ---------------------------------------------------------------------------
// One-time prep (proven): W -> RNE hi/lo bf16 in MFMA B-fragment lane order.
// Record f = (ks*8 + nt*2 + hl): 64 lanes x 16B; lane (n,q) holds
// W[nt*16+n][ks*32 + q*8 + 0..7].  256 KB -> d_ws.
// ---------------------------------------------------------------------------
__global__ __launch_bounds__(256) void router_prep(
        const float* __restrict__ W, unsigned short* __restrict__ Ws) {
    int t = blockIdx.x * 256 + threadIdx.x;  // 0..8191
    int lane = t & 63;
    int nt = (t >> 6) & 3;
    int ks = t >> 8;
    int n = lane & 15, q = lane >> 4;
    const float* src = W + (size_t)(nt * 16 + n) * D + ks * 32 + q * 8;
    u16x8 hv, lv;
#pragma unroll
    for (int j = 0; j < 8; ++j) {
        float v = src[j];
        unsigned short h = bf16_rne(v);
        hv[j] = h;
        lv[j] = bf16_rne(v - bf16_to_f(h));
    }
    size_t base = ((size_t)(ks * 8 + nt * 2) * 64 + lane) * 8;
    *(u16x8*)(Ws + base)          = hv;      // hl = 0
    *(u16x8*)(Ws + base + 64 * 8) = lv;      // hl = 1
}

// ---------------------------------------------------------------------------
// Main: r8 structure with ONE change — W staging via global_load_lds DMA
// (m97 pattern) instead of global->reg->LDS.  Removes from the serial
// per-phase path: the mid-phase vmcnt wait before WRITEW, 8 ds_write_b128
// + lgkm chain, and 32 VGPRs of W batch registers.  Gloads are issued at
// phase start, land in LDS during COMPCHUNK, and the single barrier's
// vmcnt(0)+lgkmcnt(0) drain makes them visible.  A path, MFMA order, and
// epilogue are bit-identical to r8 (passing, absmax 4.88e-4).
// ---------------------------------------------------------------------------
__global__ __launch_bounds__(TPB) void router_main(
        const float* __restrict__ x, const unsigned short* __restrict__ Ws,
        const float* __restrict__ bias, float* __restrict__ out, int T) {
    __shared__ __align__(16) union SM {
        unsigned char buf[2][CHB];          // 64 KB: double-buffered W chunks
        float ls[TOKS][E + 1];              // epilogue logits (union reuse)
    } sm;
    __shared__ float sbias[E];

    const int tid  = threadIdx.x;
    const int lane = tid & 63;
    const int wid  = tid >> 6;
    const int n    = lane & 15;
    const int q    = lane >> 4;
    const int t0   = blockIdx.x * TOKS;

    if (tid < E) sbias[tid] = bias[tid];

    const float* arow = x + (size_t)(t0 + wid * 16 + n) * D + q * 8;
    const u32x4* gws  = (const u32x4*)Ws;

    f32x4 c0 = {0.f, 0.f, 0.f, 0.f}, c1 = c0, c2 = c0, c3 = c0;

    // Named register batches only (rule #20).
    f32x4 A0u, A0v, A1u, A1v, A2u, A2v, A3u, A3v;         // A chunk (cur)
    f32x4 N0u, N0v, N1u, N1v, N2u, N2v, N3u, N3v;         // A chunk (next)

// Stage W chunk c_ into LDS buf bi_ via 8 global_load_lds (fire-and-forget).
// Wave w's instr r: lanes write buf + r*4096 + w*1024 + lane*16 (linear),
// from per-lane global src gws + c*2048 + r*256 + tid (16B each).
#define GLOADW(bi_, c_) do {                                          \
        const u32x4* _g = gws + (size_t)(c_) * 2048 + tid;            \
        char* _lb = (char*)sm.buf[bi_] + wid * 1024;                  \
        gload16(_g,        _lb);                                      \
        gload16(_g + 256,  _lb + 4096);                               \
        gload16(_g + 512,  _lb + 8192);                               \
        gload16(_g + 768,  _lb + 12288);                              \
        gload16(_g + 1024, _lb + 16384);                              \
        gload16(_g + 1280, _lb + 20480);                              \
        gload16(_g + 1536, _lb + 24576);                              \
        gload16(_g + 1792, _lb + 28672);                              \
    } while (0)

#define ISSUEA(p0u,p0v,p1u,p1v,p2u,p2v,p3u,p3v, c_) do {              \
        const float* _b = arow + (size_t)(c_) * 128;                  \
        p0u = *(const f32x4*)(_b);       p0v = *(const f32x4*)(_b + 4);   \
        p1u = *(const f32x4*)(_b + 32);  p1v = *(const f32x4*)(_b + 36);  \
        p2u = *(const f32x4*)(_b + 64);  p2v = *(const f32x4*)(_b + 68);  \
        p3u = *(const f32x4*)(_b + 96);  p3v = *(const f32x4*)(_b + 100); \
    } while (0)

#define MFMA __builtin_amdgcn_mfma_f32_16x16x32_bf16
// One MFMA k-step: A pair (au,av) against the 8 frag-records of k-step ksl.
// Accumulation order identical to all passing rounds.
#define COMPSTEP(bi_, ksl_, au_, av_) do {                            \
        bf16x8 ah, al;                                                \
        split8_rne(au_, av_, ah, al);                                 \
        const char* _p = (const char*)sm.buf[bi_] + (ksl_) * 8192 + lane * 16; \
        {                                                             \
            bf16x8 bh = *(const bf16x8*)(_p);                         \
            bf16x8 bl = *(const bf16x8*)(_p + 1024);                  \
            c0 = MFMA(ah, bh, c0, 0, 0, 0);                           \
            c0 = MFMA(al, bh, c0, 0, 0, 0);                           \
            c0 = MFMA(ah, bl, c0, 0, 0, 0);                           \
        }                                                             \
        {                                                             \
            bf16x8 bh = *(const bf16x8*)(_p + 2048);                  \
            bf16x8 bl = *(const bf16x8*)(_p + 3072);                  \
            c1 = MFMA(ah, bh, c1, 0, 0, 0);                           \
            c1 = MFMA(al, bh, c1, 0, 0, 0);                           \
            c1 = MFMA(ah, bl, c1, 0, 0, 0);                           \
        }                                                             \
        {                                                             \
            bf16x8 bh = *(const bf16x8*)(_p + 4096);                  \
            bf16x8 bl = *(const bf16x8*)(_p + 5120);                  \
            c2 = MFMA(ah, bh, c2, 0, 0, 0);                           \
            c2 = MFMA(al, bh, c2, 0, 0, 0);                           \
            c2 = MFMA(ah, bl, c2, 0, 0, 0);                           \
        }                                                             \
        {                                                             \
            bf16x8 bh = *(const bf16x8*)(_p + 6144);                  \
            bf16x8 bl = *(const bf16x8*)(_p + 7168);                  \
            c3 = MFMA(ah, bh, c3, 0, 0, 0);                           \
            c3 = MFMA(al, bh, c3, 0, 0, 0);                           \
            c3 = MFMA(ah, bl, c3, 0, 0, 0);                           \
        }                                                             \
    } while (0)

#define COMPCHUNK(bi_, p0u,p0v,p1u,p1v,p2u,p2v,p3u,p3v) do {          \
        COMPSTEP(bi_, 0, p0u, p0v);                                   \
        COMPSTEP(bi_, 1, p1u, p1v);                                   \
        COMPSTEP(bi_, 2, p2u, p2v);                                   \
        COMPSTEP(bi_, 3, p3u, p3v);                                   \
    } while (0)

    // ---- prologue: chunk 0 DMA'd into buf0, A chunk 0 into regs ----
    GLOADW(0, 0);
    ISSUEA(A0u,A0v,A1u,A1v,A2u,A2v,A3u,A3v, 0);
    __syncthreads();    // drains the gloads (vmcnt 0) -> buf0 ready

    // ---- 8 phases, one barrier each; gloads issued early land during
    //      COMPCHUNK; the barrier drain publishes them ----
    for (int c = 0; c < NCH; c += 2) {
        GLOADW(1, c + 1);
        ISSUEA(N0u,N0v,N1u,N1v,N2u,N2v,N3u,N3v, c + 1);
        COMPCHUNK(0, A0u,A0v,A1u,A1v,A2u,A2v,A3u,A3v);
        __syncthreads();
        GLOADW(0, (c + 2) & (NCH - 1));
        ISSUEA(A0u,A0v,A1u,A1v,A2u,A2v,A3u,A3v, (c + 2) & (NCH - 1));
        COMPCHUNK(1, N0u,N0v,N1u,N1v,N2u,N2v,N3u,N3v);
        __syncthreads();
    }

    // ---- epilogue: logits (+bias) into union'd LDS, softmax + top-2 ----
    // (the final barrier above drained the wrap-around gloads, so reusing
    //  buf0's space for ls is ordered-safe)
    {
        const int row = wid * 16 + q * 4;
#define STORE_C(c_, nt_) do {                                         \
            int col = (nt_) * 16 + n;                                 \
            float bv = sbias[col];                                    \
            sm.ls[row + 0][col] = c_[0] + bv;                         \
            sm.ls[row + 1][col] = c_[1] + bv;                         \
            sm.ls[row + 2][col] = c_[2] + bv;                         \
            sm.ls[row + 3][col] = c_[3] + bv;                         \
        } while (0)
        STORE_C(c0, 0); STORE_C(c1, 1); STORE_C(c2, 2); STORE_C(c3, 3);
#undef STORE_C
    }
    __syncthreads();

    if (tid < TOKS) {
        float m1 = -3.4e38f, m2 = -3.4e38f;
        int i1 = 0, i2 = 0;
        for (int e = 0; e < E; ++e) {
            float v = sm.ls[tid][e];
            if (v > m1) { m2 = m1; i2 = i1; m1 = v; i1 = e; }
            else if (v > m2) { m2 = v; i2 = e; }
        }
        float Z = 0.f;
        for (int e = 0; e < E; ++e) Z += __expf(sm.ls[tid][e] - m1);
        float inv = 1.f / Z;
        int gt = t0 + tid;
        out[(size_t)gt * 2]     = inv;                  // exp(m1-m1)/Z
        out[(size_t)gt * 2 + 1] = __expf(m2 - m1) * inv;
        float* oi = out + (size_t)T * 2;
        oi[(size_t)gt * 2]     = (float)i1;             // indices as floats
        oi[(size_t)gt * 2 + 1] = (float)i2;
    }
}

extern "C" void kernel_launch(void* const* d_in, const int* in_sizes, int n_in,
                              void* d_out, int out_size, void* d_ws, size_t ws_size,
                              hipStream_t stream) {
    const float* x = (const float*)d_in[0];
    const float* W = (const float*)d_in[1];
    const float* b = (const float*)d_in[2];
    float* out = (float*)d_out;
    unsigned short* Ws = (unsigned short*)d_ws;   // needs 256 KB
    int T = in_sizes[0] / D;                      // 32768 tokens
    hipLaunchKernelGGL(router_prep, dim3(32), dim3(256), 0, stream, W, Ws);
    hipLaunchKernelGGL(router_main, dim3(T / TOKS), dim3(TPB), 0, stream,
                       x, Ws, b, out, T);
}